// Round 6
// baseline (712.893 us; speedup 1.0000x reference)
//
#include <hip/hip_runtime.h>
#include <cstddef>
#include <cstdint>

#define Bn 256
#define Hd 128
#define Nd 2048
#define K3 384     // W row stride (3H)
#define NTILE 128  // n-tile per block
#define BPC 16     // b-values per persistent block (grid = 16 n-tiles x 16 chunks = 256)

typedef _Float16 half8 __attribute__((ext_vector_type(8)));
typedef float    float4v __attribute__((ext_vector_type(4)));

__device__ __forceinline__ float fast_tanh(float x) {
    // tanh(x) = 1 - 2/(exp(2x)+1); saturates correctly at +/-inf
    return 1.0f - __fdividef(2.0f, __expf(2.0f * x) + 1.0f);
}

// ---------------------------------------------------------------------------
// prep 1: Wf[h][k] = fp16(W[h][k]) for k<256  (static+dynamic columns)
__global__ void prep_w16(const float* __restrict__ W, _Float16* __restrict__ Wf) {
    int idx = blockIdx.x * 256 + threadIdx.x;   // 0..32767
    int h = idx >> 8, k = idx & 255;
    Wf[idx] = (_Float16)W[h * K3 + k];
}

// prep 2: c[b][h] = sum_k W[h][256+k] * dec[b][k]  (decoder term, fp32 exact)
__global__ void prep_c(const float* __restrict__ W, const float* __restrict__ dec,
                       float* __restrict__ cb) {
    __shared__ float dl[Hd];
    int b = blockIdx.x;
    int h = threadIdx.x;       // 128 threads
    dl[h] = dec[b * Hd + h];
    __syncthreads();
    float acc = 0.f;
    #pragma unroll 8
    for (int k = 0; k < Hd; ++k)
        acc = fmaf(W[h * K3 + 256 + k], dl[k], acc);
    cb[b * Hd + h] = acc;
}

// ---------------------------------------------------------------------------
// Main: PRODUCER/CONSUMER wave specialization. 256 blocks (1/CU), 512 thr.
// Evidence (R0..R5): perf tracks staged-bytes-per-sync-phase, not occupancy
// (R2: 79% occ, slower) nor prefetch depth (R5). R0 (128KB/epoch) = fastest.
// This design: 128n x 256k tile (128 KB f32 in, 64 KB f16 staged), ONE
// __syncthreads per tile, double-buffered xl (2x64 KB = 128 KB LDS).
//
// Waves 0-3 (producers): wave p streams logical k-band [64p,64p+64)
// (p<2: static, else dynamic) for all 128 n. Per chunk c(0..3): lane
// (nc=lane&31, hi=lane>>5) loads 8x float4 from rows kb+16c+8hi+j, cols
// n0+4nc -> reg transpose -> 4 half8 (k-octet ck = 8p+2c+hi contiguous) ->
// swizzled ds_write: xl[n][k] f16, phys 16B-chunk = ck ^ ((n>>1)&7).
// Latency hidden by construction: consumers never wait on staging.
//
// Waves 4-7 (consumers): wave cw covers n in [32cw,32cw+32) (2 N-tiles),
// ALL 128 h (8 M-tiles, acc[8][2]) -> v-reduction closes IN-WAVE (2 shfl),
// no LDS reduction, no extra barriers. A streamed from L2-hot Wf with
// distance-1 prefetch; acc init from cbp (decoder term, exact).
// Same validated fragment/swizzle algebra as R0/R5 (absmax 7.6e-6).
__global__ __launch_bounds__(512, 2)
void score_kernel(const float* __restrict__ shp, const float* __restrict__ dhp,
                  const _Float16* __restrict__ Wf, const float* __restrict__ cbp,
                  const float* __restrict__ v, float* __restrict__ out) {
    __shared__ __align__(16) _Float16 xl0[NTILE * 256];   // 64 KB
    __shared__ __align__(16) _Float16 xl1[NTILE * 256];   // 64 KB

    const int tid  = threadIdx.x;
    const int w    = __builtin_amdgcn_readfirstlane(tid >> 6);
    const int lane = tid & 63;
    const int qd   = lane >> 4;
    const int ln   = lane & 15;
    const int bid  = blockIdx.x;
    const int n0   = (bid & 15) * NTILE;
    const int b0   = (bid >> 4) * BPC;
    const size_t bstr = (size_t)Hd * Nd;

    if (w < 4) {
        // ================= PRODUCER =================
        const float* arr = (w < 2) ? shp : dhp;
        const int    kb  = (w & 1) * 64;          // k-row base within arr
        const int    nc  = lane & 31;
        const int    hi  = lane >> 5;
        const float* gb  = arr + (size_t)b0 * bstr
                         + (size_t)(kb + 8 * hi) * Nd + n0 + 4 * nc;

        // ---- stage tile 0 into xl0
        #pragma unroll
        for (int c2 = 0; c2 < 4; ++c2) {
            const float* src = gb + (size_t)(16 * c2) * Nd;
            float4v xv[8];
            #pragma unroll
            for (int j = 0; j < 8; ++j)
                xv[j] = *reinterpret_cast<const float4v*>(src + (size_t)j * Nd);
            const int ck = 8 * w + 2 * c2 + hi;
            #pragma unroll
            for (int r = 0; r < 4; ++r) {
                half8 e;
                #pragma unroll
                for (int j = 0; j < 8; ++j) e[j] = (_Float16)xv[j][r];
                const int n = 4 * nc + r;
                *reinterpret_cast<half8*>(&xl0[n * 256 + ((ck ^ ((n >> 1) & 7)) << 3)]) = e;
            }
        }
        __syncthreads();

        for (int it = 0; it < BPC; ++it) {
            if (it + 1 < BPC) {
                _Float16* buf = ((it + 1) & 1) ? xl1 : xl0;
                const float* gt = gb + (size_t)(it + 1) * bstr;
                #pragma unroll
                for (int c2 = 0; c2 < 4; ++c2) {
                    const float* src = gt + (size_t)(16 * c2) * Nd;
                    float4v xv[8];
                    #pragma unroll
                    for (int j = 0; j < 8; ++j)
                        xv[j] = *reinterpret_cast<const float4v*>(src + (size_t)j * Nd);
                    const int ck = 8 * w + 2 * c2 + hi;
                    #pragma unroll
                    for (int r = 0; r < 4; ++r) {
                        half8 e;
                        #pragma unroll
                        for (int j = 0; j < 8; ++j) e[j] = (_Float16)xv[j][r];
                        const int n = 4 * nc + r;
                        *reinterpret_cast<half8*>(&buf[n * 256 + ((ck ^ ((n >> 1) & 7)) << 3)]) = e;
                    }
                }
            }
            __syncthreads();
        }
    } else {
        // ================= CONSUMER =================
        const int cw = w & 3;                      // n-band: [32cw, 32cw+32)

        // persistent v fragments (32 VGPR)
        float4v vv[8];
        #pragma unroll
        for (int Mt = 0; Mt < 8; ++Mt)
            vv[Mt] = *reinterpret_cast<const float4v*>(v + Mt * 16 + qd * 4);

        __syncthreads();                           // tile 0 staged

        for (int it = 0; it < BPC; ++it) {
            const _Float16* buf = (it & 1) ? xl1 : xl0;
            const int b = b0 + it;

            // acc init with decoder term: D row = qd*4 + r
            float4v acc[8][2];
            #pragma unroll
            for (int Mt = 0; Mt < 8; ++Mt) {
                float4v c4 = *reinterpret_cast<const float4v*>(
                    cbp + (size_t)b * Hd + Mt * 16 + qd * 4);
                acc[Mt][0] = c4;
                acc[Mt][1] = c4;
            }

            // A stream from Wf (L2-hot), distance-1 prefetch.
            // A[m=ln][k=qd*8+j]; B[k=qd*8+j][n=ln].
            half8 a[8], an[8];
            #pragma unroll
            for (int Mt = 0; Mt < 8; ++Mt)
                a[Mt] = *reinterpret_cast<const half8*>(Wf + ((Mt * 16 + ln) << 8) + qd * 8);

            #pragma unroll
            for (int kt = 0; kt < 8; ++kt) {
                if (kt < 7) {
                    #pragma unroll
                    for (int Mt = 0; Mt < 8; ++Mt)
                        an[Mt] = *reinterpret_cast<const half8*>(
                            Wf + ((Mt * 16 + ln) << 8) + (kt + 1) * 32 + qd * 8);
                }
                half8 Bf[2];
                const int ckb = kt * 4 + qd;
                #pragma unroll
                for (int Nt = 0; Nt < 2; ++Nt) {
                    const int row = cw * 32 + Nt * 16 + ln;
                    Bf[Nt] = *reinterpret_cast<const half8*>(
                        &buf[row * 256 + ((ckb ^ ((row >> 1) & 7)) << 3)]);
                }
                #pragma unroll
                for (int Mt = 0; Mt < 8; ++Mt) {
                    acc[Mt][0] = __builtin_amdgcn_mfma_f32_16x16x32_f16(a[Mt], Bf[0], acc[Mt][0], 0, 0, 0);
                    acc[Mt][1] = __builtin_amdgcn_mfma_f32_16x16x32_f16(a[Mt], Bf[1], acc[Mt][1], 0, 0, 0);
                }
                if (kt < 7) {
                    #pragma unroll
                    for (int Mt = 0; Mt < 8; ++Mt) a[Mt] = an[Mt];
                }
            }

            // epilogue: score[n] = sum_h v[h]*tanh(t[h][n]) -- fully in-wave
            #pragma unroll
            for (int Nt = 0; Nt < 2; ++Nt) {
                float part = 0.f;
                #pragma unroll
                for (int Mt = 0; Mt < 8; ++Mt) {
                    #pragma unroll
                    for (int r = 0; r < 4; ++r)
                        part = fmaf(vv[Mt][r], fast_tanh(acc[Mt][Nt][r]), part);
                }
                part += __shfl_xor(part, 16);      // sum quads (h groups), same n
                part += __shfl_xor(part, 32);
                if (qd == 0)
                    out[(size_t)b * Nd + n0 + cw * 32 + Nt * 16 + ln] = part;
            }
            __syncthreads();
        }
    }
}

// ---------------------------------------------------------------------------
// softmax over n=2048 per b, in place. (validated round 1)
__global__ void softmax_k(float* __restrict__ out) {
    int b = blockIdx.x;
    float* row = out + (size_t)b * Nd;
    int tid = threadIdx.x;

    float loc[8];
    float mx = -3.4e38f;
    #pragma unroll
    for (int i = 0; i < 8; ++i) {
        loc[i] = row[tid + (i << 8)];
        mx = fmaxf(mx, loc[i]);
    }
    #pragma unroll
    for (int off = 32; off > 0; off >>= 1) mx = fmaxf(mx, __shfl_xor(mx, off));
    __shared__ float s4[4];
    if ((tid & 63) == 0) s4[tid >> 6] = mx;
    __syncthreads();
    mx = fmaxf(fmaxf(s4[0], s4[1]), fmaxf(s4[2], s4[3]));

    float sum = 0.f;
    #pragma unroll
    for (int i = 0; i < 8; ++i) {
        loc[i] = __expf(loc[i] - mx);
        sum += loc[i];
    }
    #pragma unroll
    for (int off = 32; off > 0; off >>= 1) sum += __shfl_xor(sum, off);
    __shared__ float s4b[4];
    if ((tid & 63) == 0) s4b[tid >> 6] = sum;
    __syncthreads();
    sum = s4b[0] + s4b[1] + s4b[2] + s4b[3];

    float inv = 1.0f / sum;
    #pragma unroll
    for (int i = 0; i < 8; ++i) row[tid + (i << 8)] = loc[i] * inv;
}

// ---------------------------------------------------------------------------
extern "C" void kernel_launch(void* const* d_in, const int* in_sizes, int n_in,
                              void* d_out, int out_size, void* d_ws, size_t ws_size,
                              hipStream_t stream) {
    const float* shp = (const float*)d_in[0];   // static_hidden [B,H,N]
    const float* dhp = (const float*)d_in[1];   // dynamic_hidden [B,H,N]
    const float* dec = (const float*)d_in[2];   // decoder_hidden [B,H]
    const float* v   = (const float*)d_in[3];   // [H]
    const float* W   = (const float*)d_in[4];   // [H, 3H]
    float* out = (float*)d_out;                 // [B,1,N]

    _Float16* Wf = (_Float16*)d_ws;             // 32768 halves = 64 KB
    float* cbp = (float*)((char*)d_ws + 65536); // 32768 floats = 128 KB

    hipLaunchKernelGGL(prep_w16, dim3(128), dim3(256), 0, stream, W, Wf);
    hipLaunchKernelGGL(prep_c,   dim3(Bn),  dim3(Hd),  0, stream, W, dec, cbp);
    hipLaunchKernelGGL(score_kernel, dim3((Nd / NTILE) * (Bn / BPC)), dim3(512), 0, stream,
                       shp, dhp, Wf, cbp, v, out);
    hipLaunchKernelGGL(softmax_k, dim3(Bn), dim3(256), 0, stream, out);
}

// Round 8
// 598.748 us; speedup vs baseline: 1.1906x; 1.1906x over previous
//
#include <hip/hip_runtime.h>
#include <cstddef>
#include <cstdint>

#define Bn 256
#define Hd 128
#define Nd 2048
#define K3 384     // W row stride (3H)
#define NTn 256    // n-tile per block (=> 1KB contiguous DMA rows)
#define KC 64      // k-chunk rows per iteration
#define BPC 8      // b-values per block; grid = (2048/256)*(256/8) = 256

typedef _Float16 half8 __attribute__((ext_vector_type(8)));
typedef float    float4v __attribute__((ext_vector_type(4)));
typedef unsigned int u32;

#define BAR()    __builtin_amdgcn_s_barrier()
#define SFENCE() __builtin_amdgcn_sched_barrier(0)

__device__ __forceinline__ float fast_tanh(float x) {
    // tanh(x) = 1 - 2/(exp(2x)+1); saturates correctly at +/-inf
    return 1.0f - __fdividef(2.0f, __expf(2.0f * x) + 1.0f);
}

// async global->LDS DMA, 16B per lane. LDS dest wave-uniform base; HW adds
// lane*16. Global src is PER-LANE (may carry lane offset).
__device__ __forceinline__ void dma16(const float* g, const void* l) {
    __builtin_amdgcn_global_load_lds(
        (const __attribute__((address_space(1))) u32*)(uintptr_t)g,
        (__attribute__((address_space(3))) u32*)(u32)(uintptr_t)l,
        16, 0, 0);
}

// ---------------------------------------------------------------------------
// prep 1: Wf[h][k] = fp16(W[h][k]) for k<256  (static+dynamic columns)
__global__ void prep_w16(const float* __restrict__ W, _Float16* __restrict__ Wf) {
    int idx = blockIdx.x * 256 + threadIdx.x;   // 0..32767
    int h = idx >> 8, k = idx & 255;
    Wf[idx] = (_Float16)W[h * K3 + k];
}

// prep 2: c[b][h] = sum_k W[h][256+k] * dec[b][k]  (decoder term, fp32 exact)
__global__ void prep_c(const float* __restrict__ W, const float* __restrict__ dec,
                       float* __restrict__ cb) {
    __shared__ float dl[Hd];
    int b = blockIdx.x;
    int h = threadIdx.x;       // 128 threads
    dl[h] = dec[b * Hd + h];
    __syncthreads();
    float acc = 0.f;
    #pragma unroll 8
    for (int k = 0; k < Hd; ++k)
        acc = fmaf(W[h * K3 + 256 + k], dl[k], acc);
    cb[b * Hd + h] = acc;
}

// ---------------------------------------------------------------------------
// Main: 256 blocks (1/CU), 512 thr, LDS = 128 KB (2 x 64KB raw f32 chunks).
//
// R7 synthesis: in-flight depth is NOT the limiter (R5/R7 equal at 4x depth).
// Remaining structural constant: staging segment size (256B). This design:
// NTn=256 => each dma16 = 64 lanes x 16B = ONE 1KB-CONTIGUOUS row (the m13
// 6.3TB/s pattern). k split into 4 chunks of 64 (acc persists in registers
// across chunks); CVT pass ELIMINATED: B-fragments built by ds_read_b32 of
// raw f32 (4-way bank conflict = 1.58x, ~1us/chunk, hidden under 2.6us DMA
// service) + in-register cvt. 2 barriers/iter (was 4).
//
// vmcnt discipline: per iter: [A x16 (+cbp x8 at c==0)] -> SFENCE ->
// [DMA(next) x8] -> vmcnt(8) (8 newest = next DMA; current DMA + A + cbp
// forced complete) -> BAR -> compute (reads raw[cur]) -> BAR. Final iter
// issues no DMA, waits vmcnt(0). Post-loop vmcnt(0) drain (R7 race fix: no
// global_load_lds may be outstanding at s_endpgm -- LDS is reallocated).
//
// Roles: wave w stages rows [8w,8w+8) of each chunk (chunk c: arr = c<2 ?
// static:dynamic, kbase=(c&1)*64); computes n in [32w,32w+32) x all 128 h
// (acc[8][2], 32 MFMA/iter). Epilogue in-wave (shfl over quads), no LDS red.
__global__ __launch_bounds__(512, 2)
void score_kernel(const float* __restrict__ shp, const float* __restrict__ dhp,
                  const _Float16* __restrict__ Wf, const float* __restrict__ cbp,
                  const float* __restrict__ v, float* __restrict__ out) {
    __shared__ __align__(16) float raw[2][KC * NTn];   // 2 x 64 KB, [k][n] f32 linear

    const int tid  = threadIdx.x;
    const int w    = __builtin_amdgcn_readfirstlane(tid >> 6);
    const int lane = tid & 63;
    const int qd   = lane >> 4;
    const int ln   = lane & 15;
    const int bid  = blockIdx.x;
    const int n0   = (bid & 7) * NTn;
    const int b0   = (bid >> 3) * BPC;
    const size_t bstr = (size_t)Hd * Nd;

    // persistent v fragments (h = Mt*16 + qd*4 + r)
    float4v vv[8];
    #pragma unroll
    for (int Mt = 0; Mt < 8; ++Mt)
        vv[Mt] = *reinterpret_cast<const float4v*>(v + Mt * 16 + qd * 4);

    // ---- staging helper: wave w -> rows [8w, 8w+8) of chunk c, 1KB/row
    auto stage = [&](int buf, int bi, int c) {
        const float* arr = (c < 2) ? shp : dhp;
        const int kbase  = (c & 1) * 64 + 8 * w;
        const float* g = arr + (size_t)(b0 + bi) * bstr + (size_t)kbase * Nd
                       + n0 + 4 * lane;
        const char* l = (const char*)&raw[buf][0] + (8 * w) * (NTn * 4);
        #pragma unroll
        for (int t = 0; t < 8; ++t)
            dma16(g + (size_t)t * Nd, l + t * (NTn * 4));
    };

    // ---- prologue: stage chunk 0 of b0 into buf 0
    stage(0, 0, 0);

    const int nn0 = 32 * w + ln;       // wave's n (Nt adds 16)
    float4v acc[8][2];
    half8 A[2][8];                     // [kt][Mt], 64 VGPR

    int cur = 0;
    for (int bi = 0; bi < BPC; ++bi) {
        #pragma unroll 1
        for (int c = 0; c < 4; ++c) {
            // -- A fragments for this chunk (L2-hot Wf), issued BEFORE DMA
            #pragma unroll
            for (int kt = 0; kt < 2; ++kt)
                #pragma unroll
                for (int Mt = 0; Mt < 8; ++Mt)
                    A[kt][Mt] = *reinterpret_cast<const half8*>(
                        Wf + ((Mt * 16 + ln) << 8) + c * 64 + kt * 32 + qd * 8);
            // -- acc init from cbp at chunk 0 (also pre-DMA)
            if (c == 0) {
                #pragma unroll
                for (int Mt = 0; Mt < 8; ++Mt) {
                    acc[Mt][0] = *reinterpret_cast<const float4v*>(
                        cbp + (size_t)(b0 + bi) * Hd + Mt * 16 + qd * 4);
                    acc[Mt][1] = acc[Mt][0];
                }
            }
            SFENCE();

            // -- issue next chunk's DMA (except on the very last iteration)
            const bool last = (bi == BPC - 1) && (c == 3);
            if (!last) {
                int nc = c + 1, nb = bi;
                if (nc == 4) { nc = 0; ++nb; }
                stage(cur ^ 1, nb, nc);
            }
            SFENCE();
            if (last) { asm volatile("s_waitcnt vmcnt(0)" ::: "memory"); }
            else      { asm volatile("s_waitcnt vmcnt(8)" ::: "memory"); }
            SFENCE();
            BAR();
            SFENCE();

            // -- compute on raw[cur]: B[k=qd*8+j][n], cvt f32->f16 in-reg
            const float* rc = cur ? &raw[1][0] : &raw[0][0];
            #pragma unroll
            for (int kt = 0; kt < 2; ++kt) {
                #pragma unroll
                for (int Nt = 0; Nt < 2; ++Nt) {
                    half8 Bf;
                    const int nn = nn0 + Nt * 16;
                    #pragma unroll
                    for (int j = 0; j < 8; ++j)
                        Bf[j] = (_Float16)rc[(kt * 32 + qd * 8 + j) * NTn + nn];
                    #pragma unroll
                    for (int Mt = 0; Mt < 8; ++Mt)
                        acc[Mt][Nt] = __builtin_amdgcn_mfma_f32_16x16x32_f16(
                            A[kt][Mt], Bf, acc[Mt][Nt], 0, 0, 0);
                }
            }

            // -- epilogue after last chunk: score[n] = sum_h v[h]*tanh(t[h][n])
            if (c == 3) {
                #pragma unroll
                for (int Nt = 0; Nt < 2; ++Nt) {
                    float part = 0.f;
                    #pragma unroll
                    for (int Mt = 0; Mt < 8; ++Mt)
                        #pragma unroll
                        for (int r = 0; r < 4; ++r)
                            part = fmaf(vv[Mt][r], fast_tanh(acc[Mt][Nt][r]), part);
                    part += __shfl_xor(part, 16);   // sum quads (h groups), same n
                    part += __shfl_xor(part, 32);
                    if (qd == 0)
                        out[(size_t)(b0 + bi) * Nd + n0 + 32 * w + Nt * 16 + ln] = part;
                }
            }
            SFENCE();
            BAR();                     // reads of raw[cur] done -> reusable
            cur ^= 1;
        }
    }
    asm volatile("s_waitcnt vmcnt(0)" ::: "memory");   // no DMA outstanding at endpgm
}

// ---------------------------------------------------------------------------
// softmax over n=2048 per b, in place. (validated round 1)
__global__ void softmax_k(float* __restrict__ out) {
    int b = blockIdx.x;
    float* row = out + (size_t)b * Nd;
    int tid = threadIdx.x;

    float loc[8];
    float mx = -3.4e38f;
    #pragma unroll
    for (int i = 0; i < 8; ++i) {
        loc[i] = row[tid + (i << 8)];
        mx = fmaxf(mx, loc[i]);
    }
    #pragma unroll
    for (int off = 32; off > 0; off >>= 1) mx = fmaxf(mx, __shfl_xor(mx, off));
    __shared__ float s4[4];
    if ((tid & 63) == 0) s4[tid >> 6] = mx;
    __syncthreads();
    mx = fmaxf(fmaxf(s4[0], s4[1]), fmaxf(s4[2], s4[3]));

    float sum = 0.f;
    #pragma unroll
    for (int i = 0; i < 8; ++i) {
        loc[i] = __expf(loc[i] - mx);
        sum += loc[i];
    }
    #pragma unroll
    for (int off = 32; off > 0; off >>= 1) sum += __shfl_xor(sum, off);
    __shared__ float s4b[4];
    if ((tid & 63) == 0) s4b[tid >> 6] = sum;
    __syncthreads();
    sum = s4b[0] + s4b[1] + s4b[2] + s4b[3];

    float inv = 1.0f / sum;
    #pragma unroll
    for (int i = 0; i < 8; ++i) row[tid + (i << 8)] = loc[i] * inv;
}

// ---------------------------------------------------------------------------
extern "C" void kernel_launch(void* const* d_in, const int* in_sizes, int n_in,
                              void* d_out, int out_size, void* d_ws, size_t ws_size,
                              hipStream_t stream) {
    const float* shp = (const float*)d_in[0];   // static_hidden [B,H,N]
    const float* dhp = (const float*)d_in[1];   // dynamic_hidden [B,H,N]
    const float* dec = (const float*)d_in[2];   // decoder_hidden [B,H]
    const float* v   = (const float*)d_in[3];   // [H]
    const float* W   = (const float*)d_in[4];   // [H, 3H]
    float* out = (float*)d_out;                 // [B,1,N]

    _Float16* Wf = (_Float16*)d_ws;             // 32768 halves = 64 KB
    float* cbp = (float*)((char*)d_ws + 65536); // 32768 floats = 128 KB

    hipLaunchKernelGGL(prep_w16, dim3(128), dim3(256), 0, stream, W, Wf);
    hipLaunchKernelGGL(prep_c,   dim3(Bn),  dim3(Hd),  0, stream, W, dec, cbp);
    hipLaunchKernelGGL(score_kernel, dim3((Nd / NTn) * (Bn / BPC)), dim3(512), 0, stream,
                       shp, dhp, Wf, cbp, v, out);
    hipLaunchKernelGGL(softmax_k, dim3(Bn), dim3(256), 0, stream, out);
}

// Round 9
// 512.873 us; speedup vs baseline: 1.3900x; 1.1674x over previous
//
#include <hip/hip_runtime.h>
#include <cstddef>

#define Bn 256
#define Hd 128
#define Nd 2048
#define K3 384     // W row stride (3H)

typedef _Float16 half8 __attribute__((ext_vector_type(8)));
typedef float    float4v __attribute__((ext_vector_type(4)));

#define SFENCE() __builtin_amdgcn_sched_barrier(0)

__device__ __forceinline__ float fast_tanh(float x) {
    // tanh(x) = 1 - 2/(exp(2x)+1); saturates correctly at +/-inf
    return 1.0f - __fdividef(2.0f, __expf(2.0f * x) + 1.0f);
}

// ---------------------------------------------------------------------------
// prep 1: Wf[h][k] = fp16(W[h][k]) for k<256  (static+dynamic columns)
__global__ void prep_w16(const float* __restrict__ W, _Float16* __restrict__ Wf) {
    int idx = blockIdx.x * 256 + threadIdx.x;   // 0..32767
    int h = idx >> 8, k = idx & 255;
    Wf[idx] = (_Float16)W[h * K3 + k];
}

// prep 2: c[b][h] = sum_k W[h][256+k] * dec[b][k]  (decoder term, fp32 exact)
__global__ void prep_c(const float* __restrict__ W, const float* __restrict__ dec,
                       float* __restrict__ cb) {
    __shared__ float dl[Hd];
    int b = blockIdx.x;
    int h = threadIdx.x;       // 128 threads
    dl[h] = dec[b * Hd + h];
    __syncthreads();
    float acc = 0.f;
    #pragma unroll 8
    for (int k = 0; k < Hd; ++k)
        acc = fmaf(W[h * K3 + 256 + k], dl[k], acc);
    cb[b * Hd + h] = acc;
}

// ---------------------------------------------------------------------------
// Main: the prior-session R0 structure (fastest measured: ~156us score),
// with ONE change: the dynamic-half staging is overlapped with the
// static-half MFMA. Evidence (R1..R8): per-CU read rate is ~9-13 GB/s
// across ALL structures (reg bursts, DMA, counted vmcnt, 1KB segments) --
// R0 already sits at that ceiling; its only slack is serial stage-vs-MFMA.
//
// block = (b, 128-n tile), 256 threads = 4 waves, 2 blocks/CU (66 KB LDS).
// Wave w owns h in [32w,32w+32) (2 M-tiles), all waves share 128 n (8
// N-tiles), acc[2][8], K=256 via 16x16x32 MFMA. W A-frags resident (L2-hot
// Wf). x staged to LDS fp16 [n][k], 16B-chunk XOR swizzle p = ck^((n>>1)&7).
//
// Schedule: stage static (chunks 0..15) -> sync ->
//   { hp=0: issue 16 dyn float2 loads | MFMA kt0,1 (reads chunks 0..7) |
//           cvt+write chunks of kl in i2={0,1} } ->
//   { hp=1: same for kt2,3 / i2={2,3} } -> sync -> MFMA kt4..7 -> epilogue.
// sched_barrier pins the load-issue above the MFMA cluster; the compiler
// places the vmcnt wait at the cvt (first use), so dynamic-load latency
// hides under MFMA + ds_read work. MFMA order kt0..7 unchanged => numerics
// bit-identical to the validated kernel (absmax 7.63e-6).
__global__ __launch_bounds__(256, 2)
void score_kernel(const float* __restrict__ shp, const float* __restrict__ dhp,
                  const _Float16* __restrict__ Wf, const float* __restrict__ cbp,
                  const float* __restrict__ v, float* __restrict__ out) {
    __shared__ __align__(16) _Float16 xl[128 * 256];   // 64 KB, swizzled
    __shared__ float red[4 * 128];

    const int tid  = threadIdx.x;
    const int w    = __builtin_amdgcn_readfirstlane(tid >> 6);  // wave id (SGPR)
    const int lane = tid & 63;
    const int qd   = lane >> 4;       // quad 0..3
    const int ln   = lane & 15;
    const int b    = blockIdx.y;
    const int n0   = blockIdx.x * 128;
    const int h0   = w * 32;

    // ---- A fragments (W) -> registers. A[m=lane&15][k=quad*8+j].
    half8 Af[2][8];
    #pragma unroll
    for (int Mt = 0; Mt < 2; ++Mt) {
        const _Float16* wp = Wf + ((h0 + Mt * 16 + ln) << 8) + qd * 8;
        #pragma unroll
        for (int kt = 0; kt < 8; ++kt)
            Af[Mt][kt] = *reinterpret_cast<const half8*>(wp + kt * 32);
    }

    // ---- acc init with decoder term: D row = quad*4 + reg
    float4v acc[2][8];
    #pragma unroll
    for (int Mt = 0; Mt < 2; ++Mt) {
        float4v c4 = *reinterpret_cast<const float4v*>(cbp + b * Hd + h0 + Mt * 16 + qd * 4);
        #pragma unroll
        for (int Nt = 0; Nt < 8; ++Nt) acc[Mt][Nt] = c4;
    }

    // ---- staging constants: lane covers n1, n1+1 for a 8-row k band per i
    const int n1  = 2 * lane;        // even row
    const int swz = lane & 7;        // ((n1>>1)&7) == ((n1+1)>>1)&7
    const size_t bofs = (size_t)b * (Hd * (size_t)Nd) + n0 + n1;

    // ---- phase A: stage static half (logical chunks 0..15)
    {
        const float* src = shp + bofs;
        #pragma unroll
        for (int i = 0; i < 4; ++i) {
            const int kl = i * 32 + w * 8;          // wave-uniform, 0..120
            float2 xv[8];
            #pragma unroll
            for (int j = 0; j < 8; ++j)
                xv[j] = *reinterpret_cast<const float2*>(src + (size_t)(kl + j) * Nd);
            half8 e0, e1;
            #pragma unroll
            for (int j = 0; j < 8; ++j) {
                e0[j] = (_Float16)xv[j].x;
                e1[j] = (_Float16)xv[j].y;
            }
            const int p = (kl >> 3) ^ swz;
            *reinterpret_cast<half8*>(&xl[n1 * 256 + p * 8])       = e0;
            *reinterpret_cast<half8*>(&xl[(n1 + 1) * 256 + p * 8]) = e1;
        }
    }
    __syncthreads();

    const int swr = (ln >> 1) & 7;
    const float* dsrc = dhp + bofs;

    // ---- phase B: overlap dynamic staging with static-half MFMA
    #pragma unroll
    for (int hp = 0; hp < 2; ++hp) {
        // issue 16 dynamic loads (k rows for i2 = 2hp, 2hp+1)
        float2 yv[2][8];
        #pragma unroll
        for (int i2 = 0; i2 < 2; ++i2) {
            const int kl = (2 * hp + i2) * 32 + w * 8;
            #pragma unroll
            for (int j = 0; j < 8; ++j)
                yv[i2][j] = *reinterpret_cast<const float2*>(dsrc + (size_t)(kl + j) * Nd);
        }
        SFENCE();   // pin load issue above the MFMA cluster

        // MFMA on static chunks: kt = 2hp, 2hp+1 (ckb <= 15)
        #pragma unroll
        for (int kt = 2 * hp; kt < 2 * hp + 2; ++kt) {
            half8 Bf[8];
            const int ckb = kt * 4 + qd;
            #pragma unroll
            for (int Nt = 0; Nt < 8; ++Nt) {
                const int row = Nt * 16 + ln;
                Bf[Nt] = *reinterpret_cast<const half8*>(&xl[row * 256 + ((ckb ^ swr) << 3)]);
            }
            #pragma unroll
            for (int Nt = 0; Nt < 8; ++Nt) {
                acc[0][Nt] = __builtin_amdgcn_mfma_f32_16x16x32_f16(Af[0][kt], Bf[Nt], acc[0][Nt], 0, 0, 0);
                acc[1][Nt] = __builtin_amdgcn_mfma_f32_16x16x32_f16(Af[1][kt], Bf[Nt], acc[1][Nt], 0, 0, 0);
            }
        }
        SFENCE();

        // cvt + swizzled write of the dynamic rows (chunks 16..31)
        #pragma unroll
        for (int i2 = 0; i2 < 2; ++i2) {
            const int kl = (2 * hp + i2) * 32 + w * 8;
            half8 e0, e1;
            #pragma unroll
            for (int j = 0; j < 8; ++j) {
                e0[j] = (_Float16)yv[i2][j].x;
                e1[j] = (_Float16)yv[i2][j].y;
            }
            const int p = ((128 + kl) >> 3) ^ swz;
            *reinterpret_cast<half8*>(&xl[n1 * 256 + p * 8])       = e0;
            *reinterpret_cast<half8*>(&xl[(n1 + 1) * 256 + p * 8]) = e1;
        }
    }
    __syncthreads();

    // ---- MFMA on dynamic chunks: kt 4..7
    #pragma unroll
    for (int kt = 4; kt < 8; ++kt) {
        half8 Bf[8];
        const int ckb = kt * 4 + qd;
        #pragma unroll
        for (int Nt = 0; Nt < 8; ++Nt) {
            const int row = Nt * 16 + ln;
            Bf[Nt] = *reinterpret_cast<const half8*>(&xl[row * 256 + ((ckb ^ swr) << 3)]);
        }
        #pragma unroll
        for (int Nt = 0; Nt < 8; ++Nt) {
            acc[0][Nt] = __builtin_amdgcn_mfma_f32_16x16x32_f16(Af[0][kt], Bf[Nt], acc[0][Nt], 0, 0, 0);
            acc[1][Nt] = __builtin_amdgcn_mfma_f32_16x16x32_f16(Af[1][kt], Bf[Nt], acc[1][Nt], 0, 0, 0);
        }
    }

    // ---- epilogue: score[n] = sum_m v[m] * tanh(t[m][n])
    float4v v0 = *reinterpret_cast<const float4v*>(v + h0 + qd * 4);
    float4v v1 = *reinterpret_cast<const float4v*>(v + h0 + 16 + qd * 4);
    #pragma unroll
    for (int Nt = 0; Nt < 8; ++Nt) {
        float part = 0.f;
        #pragma unroll
        for (int r = 0; r < 4; ++r) {
            part = fmaf(v0[r], fast_tanh(acc[0][Nt][r]), part);
            part = fmaf(v1[r], fast_tanh(acc[1][Nt][r]), part);
        }
        part += __shfl_xor(part, 16);   // sum quads (same n)
        part += __shfl_xor(part, 32);
        if (qd == 0) red[w * 128 + Nt * 16 + ln] = part;
    }
    __syncthreads();
    if (tid < 128) {
        float s = red[tid] + red[128 + tid] + red[256 + tid] + red[384 + tid];
        out[(size_t)b * Nd + n0 + tid] = s;
    }
}

// ---------------------------------------------------------------------------
// softmax over n=2048 per b, in place. (validated round 1)
__global__ void softmax_k(float* __restrict__ out) {
    int b = blockIdx.x;
    float* row = out + (size_t)b * Nd;
    int tid = threadIdx.x;

    float loc[8];
    float mx = -3.4e38f;
    #pragma unroll
    for (int i = 0; i < 8; ++i) {
        loc[i] = row[tid + (i << 8)];
        mx = fmaxf(mx, loc[i]);
    }
    #pragma unroll
    for (int off = 32; off > 0; off >>= 1) mx = fmaxf(mx, __shfl_xor(mx, off));
    __shared__ float s4[4];
    if ((tid & 63) == 0) s4[tid >> 6] = mx;
    __syncthreads();
    mx = fmaxf(fmaxf(s4[0], s4[1]), fmaxf(s4[2], s4[3]));

    float sum = 0.f;
    #pragma unroll
    for (int i = 0; i < 8; ++i) {
        loc[i] = __expf(loc[i] - mx);
        sum += loc[i];
    }
    #pragma unroll
    for (int off = 32; off > 0; off >>= 1) sum += __shfl_xor(sum, off);
    __shared__ float s4b[4];
    if ((tid & 63) == 0) s4b[tid >> 6] = sum;
    __syncthreads();
    sum = s4b[0] + s4b[1] + s4b[2] + s4b[3];

    float inv = 1.0f / sum;
    #pragma unroll
    for (int i = 0; i < 8; ++i) row[tid + (i << 8)] = loc[i] * inv;
}

// ---------------------------------------------------------------------------
extern "C" void kernel_launch(void* const* d_in, const int* in_sizes, int n_in,
                              void* d_out, int out_size, void* d_ws, size_t ws_size,
                              hipStream_t stream) {
    const float* shp = (const float*)d_in[0];   // static_hidden [B,H,N]
    const float* dhp = (const float*)d_in[1];   // dynamic_hidden [B,H,N]
    const float* dec = (const float*)d_in[2];   // decoder_hidden [B,H]
    const float* v   = (const float*)d_in[3];   // [H]
    const float* W   = (const float*)d_in[4];   // [H, 3H]
    float* out = (float*)d_out;                 // [B,1,N]

    _Float16* Wf = (_Float16*)d_ws;             // 32768 halves = 64 KB
    float* cbp = (float*)((char*)d_ws + 65536); // 32768 floats = 128 KB

    hipLaunchKernelGGL(prep_w16, dim3(128), dim3(256), 0, stream, W, Wf);
    hipLaunchKernelGGL(prep_c,   dim3(Bn),  dim3(Hd),  0, stream, W, dec, cbp);
    hipLaunchKernelGGL(score_kernel, dim3(Nd / 128, Bn), dim3(256), 0, stream,
                       shp, dhp, Wf, cbp, v, out);
    hipLaunchKernelGGL(softmax_k, dim3(Bn), dim3(256), 0, stream, out);
}